// Round 9
// baseline (248.719 us; speedup 1.0000x reference)
//
#include <hip/hip_runtime.h>
#include <math.h>

// Round 17: three independent structural fixes (each separately attributable):
//  - gemm_out: 128 blocks (0.5/CU -> half GPU idle) -> 64x128 tiles, 256
//    blocks, LDS 24KB.  Latency-bound tail fix.
//  - attn: drop the trailing barrier (32 of them).  With triple buffering,
//    STAGE(t+2) issued AFTER the leading barrier can only touch buf (t-1)%3,
//    which every wave finished reading before it reached that barrier.
//    One barrier/iter, steady-state vmcnt(4).
//  - cvt_all: f64-sincos table blocks moved to the FRONT (they were a
//    VALU-heavy serial tail after the memory-bound blocks drained).
// gemm_qkv, rope_tab unchanged from round 16.
#define B_ 4
#define NQ 512
#define NK 2048
#define C_ 1024
#define H_ 16
#define D_ 64
#define KK 1024

typedef __attribute__((ext_vector_type(8))) _Float16 half8;
typedef __attribute__((ext_vector_type(4))) _Float16 half4;
typedef __attribute__((ext_vector_type(4))) float float4v;

// async global->LDS, 16B per lane (wave-uniform LDS base + lane*16 by HW)
__device__ __forceinline__ void g2l16(const _Float16* g, _Float16* l)
{
    __builtin_amdgcn_global_load_lds(
        (const __attribute__((address_space(1))) unsigned int*)g,
        (__attribute__((address_space(3))) unsigned int*)l, 16, 0, 0);
}

// ---------------------------------------------------------------------------
// blocks 0..255: rope table tab[p*32+i] = (cos,sin)(p * 10000^(-i/32)).
// blocks 256..4351: W fp32->fp16.  blocks 4352..22783: q/k/v fp32->fp16.
// ---------------------------------------------------------------------------
__global__ __launch_bounds__(256) void cvt_all(const float* __restrict__ W0,
                                               const float* __restrict__ W1,
                                               const float* __restrict__ W2,
                                               const float* __restrict__ W3,
                                               const float* __restrict__ q,
                                               const float* __restrict__ k,
                                               const float* __restrict__ v,
                                               _Float16* __restrict__ W16,
                                               _Float16* __restrict__ xq,
                                               _Float16* __restrict__ xk,
                                               _Float16* __restrict__ xv,
                                               float2* __restrict__ tab)
{
    const int blk = blockIdx.x;
    if (blk < 256) {
        const int idx = blk * 256 + threadIdx.x;             // 0..65535
        const int p = idx >> 5, i = idx & 31;
        double f = 1.0;
        if (i & 1)  f *= 0.7498942093324559;    // 10^-0.125
        if (i & 2)  f *= 0.5623413251903491;    // 10^-0.25
        if (i & 4)  f *= 0.31622776601683794;   // 10^-0.5
        if (i & 8)  f *= 0.1;
        if (i & 16) f *= 0.01;
        const double ang = (double)p * f;
        const double TWO_PI = 6.2831853071795864769;
        const double INV_TWO_PI = 0.15915494309189533577;
        const float red = (float)(ang - TWO_PI * floor(ang * INV_TWO_PI));
        float s, c;
        sincosf(red, &s, &c);
        tab[idx] = make_float2(c, s);
        return;
    }
    const float* src; _Float16* dst; int row;
    if (blk < 4352) {
        const int b1 = blk - 256;
        const int w = b1 >> 10; row = b1 & 1023;
        src = (w == 0) ? W0 : (w == 1) ? W1 : (w == 2) ? W2 : W3;
        dst = W16 + ((size_t)w << 20);
    } else {
        const int b2 = blk - 4352;
        if (b2 < 2048)       { src = q; dst = xq; row = b2; }
        else if (b2 < 10240) { src = k; dst = xk; row = b2 - 2048; }
        else                 { src = v; dst = xv; row = b2 - 10240; }
    }
    const int col = threadIdx.x * 4;
    float4 f = *(const float4*)(src + (size_t)row * 1024 + col);
    half4 h;
    h[0] = (_Float16)f.x; h[1] = (_Float16)f.y;
    h[2] = (_Float16)f.z; h[3] = (_Float16)f.w;
    *(half4*)(dst + (size_t)row * 1024 + col) = h;
}

// ---------------------------------------------------------------------------
// 128x128 tile, BK=64, 4 waves, 4x4 16x16x32 MFMA; global_load_lds staging
// with XOR-octet swizzle (proven conflict-free).  Round-4 exact.
// mode 0: fp16 scatter [B,H,1<<nsh,64]; mode 2: transposed [B,H,64,NK].
// ---------------------------------------------------------------------------
__device__ __forceinline__ void gemm_body(const _Float16* __restrict__ A,
                                          const _Float16* __restrict__ Bw,
                                          _Float16* __restrict__ Yh,
                                          int mode, int nsh, int m0, int n0,
                                          _Float16* sA, _Float16* sB)
{
    const int tid = threadIdx.x;
    const int lane = tid & 63, wave = tid >> 6;
    const int wm = (wave >> 1) * 64, wn = (wave & 1) * 64;
    const int fm = lane & 15, quad = lane >> 4;

    const int srow = wave * 32 + (lane >> 3);
    const int soct = (lane & 7) ^ (srow & 7);
    const _Float16* gA = A  + (size_t)(m0 + srow) * KK + soct * 8;
    const _Float16* gB = Bw + (size_t)(n0 + srow) * KK + soct * 8;

    float4v acc[4][4];
    #pragma unroll
    for (int i = 0; i < 4; ++i)
        #pragma unroll
        for (int j = 0; j < 4; ++j)
            #pragma unroll
            for (int e = 0; e < 4; ++e) acc[i][j][e] = 0.0f;

    for (int k0 = 0; k0 < KK; k0 += 64) {
        __syncthreads();
        #pragma unroll
        for (int u = 0; u < 4; ++u) {
            g2l16(gA + (size_t)u * 8 * KK + k0, &sA[(wave * 32 + u * 8) * 64]);
            g2l16(gB + (size_t)u * 8 * KK + k0, &sB[(wave * 32 + u * 8) * 64]);
        }
        __syncthreads();

        #pragma unroll
        for (int ks = 0; ks < 2; ++ks) {
            const int po = ((ks * 4 + quad) ^ (fm & 7)) * 8;
            half8 a[4], b[4];
            #pragma unroll
            for (int i = 0; i < 4; ++i) {
                a[i] = *(const half8*)&sA[(wm + i * 16 + fm) * 64 + po];
                b[i] = *(const half8*)&sB[(wn + i * 16 + fm) * 64 + po];
            }
            __builtin_amdgcn_s_setprio(1);
            #pragma unroll
            for (int i = 0; i < 4; ++i)
                #pragma unroll
                for (int j = 0; j < 4; ++j)
                    acc[i][j] = __builtin_amdgcn_mfma_f32_16x16x32_f16(a[i], b[j], acc[i][j], 0, 0, 0);
            __builtin_amdgcn_s_setprio(0);
        }
    }

    const int rr = quad * 4;
    if (mode == 0) {
        const int nmask = (1 << nsh) - 1;
        #pragma unroll
        for (int i = 0; i < 4; ++i)
            #pragma unroll
            for (int r = 0; r < 4; ++r) {
                const int m = m0 + wm + i * 16 + rr + r;
                const int b = m >> nsh, n = m & nmask;
                #pragma unroll
                for (int j = 0; j < 4; ++j) {
                    const int c = n0 + wn + j * 16 + fm;
                    Yh[((((size_t)b * H_ + (c >> 6)) << nsh) + n) * 64 + (c & 63)] = (_Float16)acc[i][j][r];
                }
            }
    } else {
        const int nmask = (1 << nsh) - 1;
        #pragma unroll
        for (int i = 0; i < 4; ++i)
            #pragma unroll
            for (int r = 0; r < 4; ++r) {
                const int m = m0 + wm + i * 16 + rr + r;
                const int b = m >> nsh, n = m & nmask;
                #pragma unroll
                for (int j = 0; j < 4; ++j) {
                    const int c = n0 + wn + j * 16 + fm;
                    Yh[(((size_t)(b * H_ + (c >> 6)) * 64) + (c & 63)) * NK + n] = (_Float16)acc[i][j][r];
                }
            }
    }
}

// Q/K/V projections, XCD-grouped linear grid of 1152 blocks (round-4 exact).
__global__ __launch_bounds__(256) void gemm_qkv(const _Float16* __restrict__ xq,
                                                const _Float16* __restrict__ xk,
                                                const _Float16* __restrict__ xv,
                                                const _Float16* __restrict__ W16,
                                                _Float16* __restrict__ qhp,
                                                _Float16* __restrict__ khp,
                                                _Float16* __restrict__ vtp)
{
    __shared__ _Float16 sA[128 * 64];
    __shared__ _Float16 sB[128 * 64];

    const int lbid = blockIdx.x;            // 0..1151
    const int xcd = lbid & 7;
    const int seq = lbid >> 3;              // 0..143
    const int y = xcd + 8 * (seq >> 3);     // m-panel 0..143
    const int n0 = (seq & 7) * 128;

    if (y < 64)
        gemm_body(xk, W16 + (1u << 20), khp, 0, 11, y * 128, n0, sA, sB);
    else if (y < 128)
        gemm_body(xv, W16 + (2u << 20), vtp, 2, 11, (y - 64) * 128, n0, sA, sB);
    else
        gemm_body(xq, W16, qhp, 0, 9, (y - 128) * 128, n0, sA, sB);
}

// ---------------------------------------------------------------------------
// Output projection: 64x128 tile, 256 blocks (was 128 = 0.5 block/CU).
// 4 waves, each 32x64 (acc[2][4]).  A: 64 rows (2 g2l calls/wave);
// B: 128 rows (4 calls/wave).  LDS 24KB.  fp32 out + bias.
// ---------------------------------------------------------------------------
__global__ __launch_bounds__(256) void gemm_out(const _Float16* __restrict__ A,
                                                const _Float16* __restrict__ Bw,
                                                float* __restrict__ Yf,
                                                const float* __restrict__ bias)
{
    __shared__ _Float16 sA[64 * 64];
    __shared__ _Float16 sB[128 * 64];

    const int tid = threadIdx.x;
    const int lane = tid & 63, wave = tid >> 6;
    const int n0 = blockIdx.x * 128, m0 = blockIdx.y * 64;
    const int wm = (wave >> 1) * 32, wn = (wave & 1) * 64;
    const int fm = lane & 15, quad = lane >> 4;

    const int r0 = lane >> 3;
    const int srowA = wave * 16 + r0;
    const int srowB = wave * 32 + r0;
    const _Float16* gA = A  + (size_t)(m0 + srowA) * KK + (((lane & 7) ^ r0) * 8);
    const _Float16* gB = Bw + (size_t)(n0 + srowB) * KK + (((lane & 7) ^ r0) * 8);

    float4v acc[2][4];
    #pragma unroll
    for (int i = 0; i < 2; ++i)
        #pragma unroll
        for (int j = 0; j < 4; ++j)
            #pragma unroll
            for (int e = 0; e < 4; ++e) acc[i][j][e] = 0.0f;

    for (int k0 = 0; k0 < KK; k0 += 64) {
        __syncthreads();
        #pragma unroll
        for (int u = 0; u < 2; ++u)
            g2l16(gA + (size_t)u * 8 * KK + k0, &sA[(wave * 16 + u * 8) * 64]);
        #pragma unroll
        for (int u = 0; u < 4; ++u)
            g2l16(gB + (size_t)u * 8 * KK + k0, &sB[(wave * 32 + u * 8) * 64]);
        __syncthreads();

        #pragma unroll
        for (int ks = 0; ks < 2; ++ks) {
            const int po = ((ks * 4 + quad) ^ (fm & 7)) * 8;
            half8 a[2], b[4];
            #pragma unroll
            for (int i = 0; i < 2; ++i)
                a[i] = *(const half8*)&sA[(wm + i * 16 + fm) * 64 + po];
            #pragma unroll
            for (int j = 0; j < 4; ++j)
                b[j] = *(const half8*)&sB[(wn + j * 16 + fm) * 64 + po];
            __builtin_amdgcn_s_setprio(1);
            #pragma unroll
            for (int i = 0; i < 2; ++i)
                #pragma unroll
                for (int j = 0; j < 4; ++j)
                    acc[i][j] = __builtin_amdgcn_mfma_f32_16x16x32_f16(a[i], b[j], acc[i][j], 0, 0, 0);
            __builtin_amdgcn_s_setprio(0);
        }
    }

    const int rr = quad * 4;
    #pragma unroll
    for (int i = 0; i < 2; ++i)
        #pragma unroll
        for (int r = 0; r < 4; ++r) {
            const int m = m0 + wm + i * 16 + rr + r;
            #pragma unroll
            for (int j = 0; j < 4; ++j) {
                const int c = n0 + wn + j * 16 + fm;
                Yf[(size_t)m * 1024 + c] = acc[i][j][r] + bias[c];
            }
        }
}

// ---------------------------------------------------------------------------
// Table-driven RoPE on qh and kh (in place).  One thread = 4 rotate-half
// pairs of one row.  Pure HBM-bound.  q rows get scale 0.125 (D^-0.5).
// ---------------------------------------------------------------------------
__global__ __launch_bounds__(256) void rope_tab(_Float16* __restrict__ qh,
                                                _Float16* __restrict__ kh,
                                                const int* __restrict__ qpos,
                                                const int* __restrict__ kpos,
                                                const float2* __restrict__ tab)
{
    const int idx = blockIdx.x * 256 + threadIdx.x;
    const int row = idx >> 3;
    const int d0 = (idx & 7) * 4;               // 0,4,...,28

    _Float16* ptr; int p; float scale;
    if (row < 32768) {                          // q: 4*16*512 rows
        ptr = qh + (size_t)row * 64;
        p = qpos[(row >> 13) * 512 + (row & 511)];
        scale = 0.125f;
    } else {                                    // k: 4*16*2048 rows
        const int rk = row - 32768;
        ptr = kh + (size_t)rk * 64;
        p = kpos[(rk >> 15) * 2048 + (rk & 2047)];
        scale = 1.0f;
    }

    half4 x1 = *(const half4*)(ptr + d0);
    half4 x2 = *(const half4*)(ptr + d0 + 32);
    const float2* tb = tab + p * 32 + d0;
    half4 o1, o2;
    #pragma unroll
    for (int u = 0; u < 4; ++u) {
        const float2 cs = tb[u];
        const float a = (float)x1[u], b = (float)x2[u];
        o1[u] = (_Float16)((a * cs.x - b * cs.y) * scale);
        o2[u] = (_Float16)((b * cs.x + a * cs.y) * scale);
    }
    *(half4*)(ptr + d0)      = o1;
    *(half4*)(ptr + d0 + 32) = o2;
}

// ---------------------------------------------------------------------------
// Fused flash attention.  Grid 512 = qoct(8) x bh(64); 4 waves/block.
// K/V triple-buffered, depth-2 prefetch, counted vmcnt.  ONE barrier/iter:
// STAGE(t+2) issued after the barrier touches buf (t-1)%3, which every wave
// finished reading before it reached that barrier (it completed compute t-1).
// Per iter: vmcnt(4) | bar | STAGE(t+2) | compute(t).
// ---------------------------------------------------------------------------
__global__ __launch_bounds__(256) void attn_fused(const _Float16* __restrict__ qh,
                                                  const _Float16* __restrict__ kh,
                                                  const _Float16* __restrict__ vt,
                                                  _Float16* __restrict__ xw16)
{
    __shared__ _Float16 sK[3][64 * 64];
    __shared__ _Float16 sV[3][64 * 64];
    __shared__ _Float16 ps[4][16][66];

    const int tid = threadIdx.x;
    const int lane = tid & 63, wv = tid >> 6;   // 4 waves
    const int bhi = blockIdx.x & 63;            // XCD key
    const int qoct = blockIdx.x >> 6;           // 0..7
    const size_t bh = (size_t)bhi;
    const int qt = qoct * 4 + wv;               // q-tile 0..31 (16 queries)

    const int fm = lane & 15;
    const int quad = lane >> 4;
    const int fq = quad * 8;

    const _Float16* kb = kh + bh * NK * 64;
    const _Float16* vb = vt + bh * (size_t)64 * NK;

    // staging: wave wv covers tile rows wv*16 + u*8 + r0, u=0,1
    const int r0 = lane >> 3;
    const int c4 = lane & 7;
    const int sch = c4 ^ r0;
    const _Float16* gK = kb + (size_t)(wv * 16 + r0) * 64 + sch * 8;
    const _Float16* gV = vb + (size_t)(wv * 16 + r0) * NK + sch * 8;

#define STAGE(bf, t) do {                                                     \
        g2l16(gK + (size_t)(t) * 4096,        &sK[bf][(wv * 16) * 64]);       \
        g2l16(gK + (size_t)(t) * 4096 + 512,  &sK[bf][(wv * 16 + 8) * 64]);   \
        g2l16(gV + (t) * 64,                  &sV[bf][(wv * 16) * 64]);       \
        g2l16(gV + (size_t)8 * NK + (t) * 64, &sV[bf][(wv * 16 + 8) * 64]);   \
    } while (0)

    const _Float16* qb = qh + (bh * NQ + (size_t)qt * 16) * 64;
    half8 aq[2];
    aq[0] = *(const half8*)(qb + (size_t)fm * 64 + fq);
    aq[1] = *(const half8*)(qb + (size_t)fm * 64 + 32 + fq);

    float l_acc[4] = {};
    float4v O[4];
    #pragma unroll
    for (int j = 0; j < 4; ++j)
        #pragma unroll
        for (int e = 0; e < 4; ++e) O[j][e] = 0.0f;

    const float4v z4 = {0.0f, 0.0f, 0.0f, 0.0f};

    STAGE(0, 0);
    STAGE(1, 1);

    for (int it = 0; it < 32; ++it) {
        const int cur = it % 3;

        // counted wait: own 4 calls of tile it retired; deeper stay in flight.
        if (it < 31) asm volatile("s_waitcnt vmcnt(4)" ::: "memory");
        else         asm volatile("s_waitcnt vmcnt(0)" ::: "memory");
        __builtin_amdgcn_sched_barrier(0);
        __builtin_amdgcn_s_barrier();           // tile it visible to all waves
        __builtin_amdgcn_sched_barrier(0);

        if (it + 2 < 32)
            STAGE((it + 2) % 3, it + 2);        // overwrites buf (it-1)%3: safe

        const _Float16* Kc = sK[cur];
        const _Float16* Vc = sV[cur];

        half8 bk[4][2];
        #pragma unroll
        for (int j = 0; j < 4; ++j)
            #pragma unroll
            for (int ks = 0; ks < 2; ++ks)
                bk[j][ks] = *(const half8*)&Kc[(j * 16 + fm) * 64 + (((ks * 4 + quad) ^ (fm & 7)) * 8)];

        float4v s[4];
        __builtin_amdgcn_s_setprio(1);
        #pragma unroll
        for (int j = 0; j < 4; ++j) {
            s[j] = __builtin_amdgcn_mfma_f32_16x16x32_f16(aq[0], bk[j][0], z4, 0, 0, 0);
            s[j] = __builtin_amdgcn_mfma_f32_16x16x32_f16(aq[1], bk[j][1], s[j], 0, 0, 0);
        }
        __builtin_amdgcn_s_setprio(0);

        half8 bv[4][2];
        #pragma unroll
        for (int j = 0; j < 4; ++j)
            #pragma unroll
            for (int ks = 0; ks < 2; ++ks)
                bv[j][ks] = *(const half8*)&Vc[(j * 16 + fm) * 64 + (((ks * 4 + quad) ^ (fm & 7)) * 8)];

        // P = exp(s) (scores pre-scaled by 0.125 in rope; fixed max 0 safe)
        #pragma unroll
        for (int j = 0; j < 4; ++j)
            #pragma unroll
            for (int r = 0; r < 4; ++r) {
                const float p = __expf(s[j][r]);
                l_acc[r] += p;
                ps[wv][quad * 4 + r][16 * j + fm] = (_Float16)p;
            }

        __builtin_amdgcn_s_setprio(1);
        #pragma unroll
        for (int ks = 0; ks < 2; ++ks) {
            half8 pa = *(const half8*)&ps[wv][fm][ks * 32 + fq];
            #pragma unroll
            for (int j = 0; j < 4; ++j)
                O[j] = __builtin_amdgcn_mfma_f32_16x16x32_f16(pa, bv[j][ks], O[j], 0, 0, 0);
        }
        __builtin_amdgcn_s_setprio(0);
    }
#undef STAGE

    // Epilogue: this wave exclusively owns its 16 queries -> direct write.
    #pragma unroll
    for (int r = 0; r < 4; ++r) {
        float l = l_acc[r];
        l += __shfl_xor(l, 1);
        l += __shfl_xor(l, 2);
        l += __shfl_xor(l, 4);
        l += __shfl_xor(l, 8);
        const float inv = 1.0f / l;
        const int qr = quad * 4 + r;
        const int row = (bhi >> 4) * 512 + qt * 16 + qr;
        #pragma unroll
        for (int j = 0; j < 4; ++j) {
            const int col = (bhi & 15) * 64 + j * 16 + fm;
            xw16[(size_t)row * 1024 + col] = (_Float16)(O[j][r] * inv);
        }
    }
}

// ---------------------------------------------------------------------------
extern "C" void kernel_launch(void* const* d_in, const int* in_sizes, int n_in,
                              void* d_out, int out_size, void* d_ws, size_t ws_size,
                              hipStream_t stream)
{
    const float* query = (const float*)d_in[0];
    const float* key   = (const float*)d_in[1];
    const float* value = (const float*)d_in[2];
    const int*   qpos  = (const int*)d_in[3];
    const int*   kpos  = (const int*)d_in[4];
    const float* Wq    = (const float*)d_in[5];
    const float* Wk    = (const float*)d_in[6];
    const float* Wv    = (const float*)d_in[7];
    const float* Wp    = (const float*)d_in[8];
    const float* bp    = (const float*)d_in[9];
    float* out = (float*)d_out;

    // ws layout (MiB), 80 total:
    //  0..16 : xk16 [8192][1024] fp16 (free after gemm_qkv)
    // 16..32 : xv16 [8192][1024] fp16 (free after gemm_qkv)
    // 32..36 : xq16 [2048][1024] fp16 -> reused as xw16 (attn out)
    // 36..44 : W16 x4 slots (Wq,Wk,Wv,Wp)
    // 44..48 : qh  [B,H,512,64] fp16
    // 48..64 : kh  [B,H,2048,64] fp16
    // 64..80 : vt  [B,H,64,2048] fp16
    // rope table tab (512KB) lives in d_out (dead until gemm_out overwrites).
    char* ws = (char*)d_ws;
    _Float16* xk16  = (_Float16*)(ws);
    _Float16* xv16  = (_Float16*)(ws + (16u << 20));
    _Float16* xq16  = (_Float16*)(ws + (32u << 20));
    _Float16* W16   = (_Float16*)(ws + (36u << 20));
    _Float16* qhp   = (_Float16*)(ws + (44u << 20));
    _Float16* khp   = (_Float16*)(ws + (48u << 20));
    _Float16* vtp   = (_Float16*)(ws + (64u << 20));
    float2*   tab   = (float2*)d_out;            // scratch until gemm_out

    cvt_all<<<22784, 256, 0, stream>>>(Wq, Wk, Wv, Wp, query, key, value,
                                       W16, xq16, xk16, xv16, tab);

    gemm_qkv<<<1152, 256, 0, stream>>>(xq16, xk16, xv16, W16, qhp, khp, vtp);

    rope_tab<<<5120, 256, 0, stream>>>(qhp, khp, qpos, kpos, tab);

    attn_fused<<<512, 256, 0, stream>>>(qhp, khp, vtp, xq16);

    gemm_out<<<dim3(8, 32), 256, 0, stream>>>(xq16, W16 + (3u << 20), out, bp);
}

// Round 10
// 237.859 us; speedup vs baseline: 1.0457x; 1.0457x over previous
//
#include <hip/hip_runtime.h>
#include <math.h>

// Round 18: attn split-by-key-half inside the shared tile.
//  - Fixed-max softmax => partials ADD (no rescale): O=O0+O1, l=l0+l1.
//  - 8 waves/block (512 thr), wave (qt4 = w&3, kh2 = w>>2): all 8 waves share
//    the SAME staged K/V tiles; each computes half the keys of its q-tile.
//    Per-wave per-iter: 4 QK MFMA + 8 exp/ps + 4 PV MFMA (was 8/16/8).
//  - Waves/CU 8 -> 16 (LDS 56.5KB -> 2 blocks/CU, grid 512 unchanged);
//    per-iter critical path halved.  Combine: one LDS add, reusing sK/sV.
//  - Staging: 2 g2l/wave/tile, steady vmcnt(2); same triple-buffer
//    single-barrier skeleton proven in rounds 16-17.
// Everything else byte-identical to round 17.
#define B_ 4
#define NQ 512
#define NK 2048
#define C_ 1024
#define H_ 16
#define D_ 64
#define KK 1024

typedef __attribute__((ext_vector_type(8))) _Float16 half8;
typedef __attribute__((ext_vector_type(4))) _Float16 half4;
typedef __attribute__((ext_vector_type(4))) float float4v;

// async global->LDS, 16B per lane (wave-uniform LDS base + lane*16 by HW)
__device__ __forceinline__ void g2l16(const _Float16* g, _Float16* l)
{
    __builtin_amdgcn_global_load_lds(
        (const __attribute__((address_space(1))) unsigned int*)g,
        (__attribute__((address_space(3))) unsigned int*)l, 16, 0, 0);
}

// ---------------------------------------------------------------------------
// blocks 0..255: rope table tab[p*32+i] = (cos,sin)(p * 10000^(-i/32)).
// blocks 256..4351: W fp32->fp16.  blocks 4352..22783: q/k/v fp32->fp16.
// ---------------------------------------------------------------------------
__global__ __launch_bounds__(256) void cvt_all(const float* __restrict__ W0,
                                               const float* __restrict__ W1,
                                               const float* __restrict__ W2,
                                               const float* __restrict__ W3,
                                               const float* __restrict__ q,
                                               const float* __restrict__ k,
                                               const float* __restrict__ v,
                                               _Float16* __restrict__ W16,
                                               _Float16* __restrict__ xq,
                                               _Float16* __restrict__ xk,
                                               _Float16* __restrict__ xv,
                                               float2* __restrict__ tab)
{
    const int blk = blockIdx.x;
    if (blk < 256) {
        const int idx = blk * 256 + threadIdx.x;             // 0..65535
        const int p = idx >> 5, i = idx & 31;
        double f = 1.0;
        if (i & 1)  f *= 0.7498942093324559;    // 10^-0.125
        if (i & 2)  f *= 0.5623413251903491;    // 10^-0.25
        if (i & 4)  f *= 0.31622776601683794;   // 10^-0.5
        if (i & 8)  f *= 0.1;
        if (i & 16) f *= 0.01;
        const double ang = (double)p * f;
        const double TWO_PI = 6.2831853071795864769;
        const double INV_TWO_PI = 0.15915494309189533577;
        const float red = (float)(ang - TWO_PI * floor(ang * INV_TWO_PI));
        float s, c;
        sincosf(red, &s, &c);
        tab[idx] = make_float2(c, s);
        return;
    }
    const float* src; _Float16* dst; int row;
    if (blk < 4352) {
        const int b1 = blk - 256;
        const int w = b1 >> 10; row = b1 & 1023;
        src = (w == 0) ? W0 : (w == 1) ? W1 : (w == 2) ? W2 : W3;
        dst = W16 + ((size_t)w << 20);
    } else {
        const int b2 = blk - 4352;
        if (b2 < 2048)       { src = q; dst = xq; row = b2; }
        else if (b2 < 10240) { src = k; dst = xk; row = b2 - 2048; }
        else                 { src = v; dst = xv; row = b2 - 10240; }
    }
    const int col = threadIdx.x * 4;
    float4 f = *(const float4*)(src + (size_t)row * 1024 + col);
    half4 h;
    h[0] = (_Float16)f.x; h[1] = (_Float16)f.y;
    h[2] = (_Float16)f.z; h[3] = (_Float16)f.w;
    *(half4*)(dst + (size_t)row * 1024 + col) = h;
}

// ---------------------------------------------------------------------------
// 128x128 tile, BK=64, 4 waves, 4x4 16x16x32 MFMA; global_load_lds staging
// with XOR-octet swizzle (proven conflict-free).  Round-4 exact.
// mode 0: fp16 scatter [B,H,1<<nsh,64]; mode 2: transposed [B,H,64,NK].
// ---------------------------------------------------------------------------
__device__ __forceinline__ void gemm_body(const _Float16* __restrict__ A,
                                          const _Float16* __restrict__ Bw,
                                          _Float16* __restrict__ Yh,
                                          int mode, int nsh, int m0, int n0,
                                          _Float16* sA, _Float16* sB)
{
    const int tid = threadIdx.x;
    const int lane = tid & 63, wave = tid >> 6;
    const int wm = (wave >> 1) * 64, wn = (wave & 1) * 64;
    const int fm = lane & 15, quad = lane >> 4;

    const int srow = wave * 32 + (lane >> 3);
    const int soct = (lane & 7) ^ (srow & 7);
    const _Float16* gA = A  + (size_t)(m0 + srow) * KK + soct * 8;
    const _Float16* gB = Bw + (size_t)(n0 + srow) * KK + soct * 8;

    float4v acc[4][4];
    #pragma unroll
    for (int i = 0; i < 4; ++i)
        #pragma unroll
        for (int j = 0; j < 4; ++j)
            #pragma unroll
            for (int e = 0; e < 4; ++e) acc[i][j][e] = 0.0f;

    for (int k0 = 0; k0 < KK; k0 += 64) {
        __syncthreads();
        #pragma unroll
        for (int u = 0; u < 4; ++u) {
            g2l16(gA + (size_t)u * 8 * KK + k0, &sA[(wave * 32 + u * 8) * 64]);
            g2l16(gB + (size_t)u * 8 * KK + k0, &sB[(wave * 32 + u * 8) * 64]);
        }
        __syncthreads();

        #pragma unroll
        for (int ks = 0; ks < 2; ++ks) {
            const int po = ((ks * 4 + quad) ^ (fm & 7)) * 8;
            half8 a[4], b[4];
            #pragma unroll
            for (int i = 0; i < 4; ++i) {
                a[i] = *(const half8*)&sA[(wm + i * 16 + fm) * 64 + po];
                b[i] = *(const half8*)&sB[(wn + i * 16 + fm) * 64 + po];
            }
            __builtin_amdgcn_s_setprio(1);
            #pragma unroll
            for (int i = 0; i < 4; ++i)
                #pragma unroll
                for (int j = 0; j < 4; ++j)
                    acc[i][j] = __builtin_amdgcn_mfma_f32_16x16x32_f16(a[i], b[j], acc[i][j], 0, 0, 0);
            __builtin_amdgcn_s_setprio(0);
        }
    }

    const int rr = quad * 4;
    if (mode == 0) {
        const int nmask = (1 << nsh) - 1;
        #pragma unroll
        for (int i = 0; i < 4; ++i)
            #pragma unroll
            for (int r = 0; r < 4; ++r) {
                const int m = m0 + wm + i * 16 + rr + r;
                const int b = m >> nsh, n = m & nmask;
                #pragma unroll
                for (int j = 0; j < 4; ++j) {
                    const int c = n0 + wn + j * 16 + fm;
                    Yh[((((size_t)b * H_ + (c >> 6)) << nsh) + n) * 64 + (c & 63)] = (_Float16)acc[i][j][r];
                }
            }
    } else {
        const int nmask = (1 << nsh) - 1;
        #pragma unroll
        for (int i = 0; i < 4; ++i)
            #pragma unroll
            for (int r = 0; r < 4; ++r) {
                const int m = m0 + wm + i * 16 + rr + r;
                const int b = m >> nsh, n = m & nmask;
                #pragma unroll
                for (int j = 0; j < 4; ++j) {
                    const int c = n0 + wn + j * 16 + fm;
                    Yh[(((size_t)(b * H_ + (c >> 6)) * 64) + (c & 63)) * NK + n] = (_Float16)acc[i][j][r];
                }
            }
    }
}

// Q/K/V projections, XCD-grouped linear grid of 1152 blocks (round-4 exact).
__global__ __launch_bounds__(256) void gemm_qkv(const _Float16* __restrict__ xq,
                                                const _Float16* __restrict__ xk,
                                                const _Float16* __restrict__ xv,
                                                const _Float16* __restrict__ W16,
                                                _Float16* __restrict__ qhp,
                                                _Float16* __restrict__ khp,
                                                _Float16* __restrict__ vtp)
{
    __shared__ _Float16 sA[128 * 64];
    __shared__ _Float16 sB[128 * 64];

    const int lbid = blockIdx.x;            // 0..1151
    const int xcd = lbid & 7;
    const int seq = lbid >> 3;              // 0..143
    const int y = xcd + 8 * (seq >> 3);     // m-panel 0..143
    const int n0 = (seq & 7) * 128;

    if (y < 64)
        gemm_body(xk, W16 + (1u << 20), khp, 0, 11, y * 128, n0, sA, sB);
    else if (y < 128)
        gemm_body(xv, W16 + (2u << 20), vtp, 2, 11, (y - 64) * 128, n0, sA, sB);
    else
        gemm_body(xq, W16, qhp, 0, 9, (y - 128) * 128, n0, sA, sB);
}

// ---------------------------------------------------------------------------
// Output projection: 64x128 tile, 256 blocks.  4 waves, each 32x64.
// ---------------------------------------------------------------------------
__global__ __launch_bounds__(256) void gemm_out(const _Float16* __restrict__ A,
                                                const _Float16* __restrict__ Bw,
                                                float* __restrict__ Yf,
                                                const float* __restrict__ bias)
{
    __shared__ _Float16 sA[64 * 64];
    __shared__ _Float16 sB[128 * 64];

    const int tid = threadIdx.x;
    const int lane = tid & 63, wave = tid >> 6;
    const int n0 = blockIdx.x * 128, m0 = blockIdx.y * 64;
    const int wm = (wave >> 1) * 32, wn = (wave & 1) * 64;
    const int fm = lane & 15, quad = lane >> 4;

    const int r0 = lane >> 3;
    const int srowA = wave * 16 + r0;
    const int srowB = wave * 32 + r0;
    const _Float16* gA = A  + (size_t)(m0 + srowA) * KK + (((lane & 7) ^ r0) * 8);
    const _Float16* gB = Bw + (size_t)(n0 + srowB) * KK + (((lane & 7) ^ r0) * 8);

    float4v acc[2][4];
    #pragma unroll
    for (int i = 0; i < 2; ++i)
        #pragma unroll
        for (int j = 0; j < 4; ++j)
            #pragma unroll
            for (int e = 0; e < 4; ++e) acc[i][j][e] = 0.0f;

    for (int k0 = 0; k0 < KK; k0 += 64) {
        __syncthreads();
        #pragma unroll
        for (int u = 0; u < 2; ++u)
            g2l16(gA + (size_t)u * 8 * KK + k0, &sA[(wave * 16 + u * 8) * 64]);
        #pragma unroll
        for (int u = 0; u < 4; ++u)
            g2l16(gB + (size_t)u * 8 * KK + k0, &sB[(wave * 32 + u * 8) * 64]);
        __syncthreads();

        #pragma unroll
        for (int ks = 0; ks < 2; ++ks) {
            const int po = ((ks * 4 + quad) ^ (fm & 7)) * 8;
            half8 a[2], b[4];
            #pragma unroll
            for (int i = 0; i < 2; ++i)
                a[i] = *(const half8*)&sA[(wm + i * 16 + fm) * 64 + po];
            #pragma unroll
            for (int j = 0; j < 4; ++j)
                b[j] = *(const half8*)&sB[(wn + j * 16 + fm) * 64 + po];
            __builtin_amdgcn_s_setprio(1);
            #pragma unroll
            for (int i = 0; i < 2; ++i)
                #pragma unroll
                for (int j = 0; j < 4; ++j)
                    acc[i][j] = __builtin_amdgcn_mfma_f32_16x16x32_f16(a[i], b[j], acc[i][j], 0, 0, 0);
            __builtin_amdgcn_s_setprio(0);
        }
    }

    const int rr = quad * 4;
    #pragma unroll
    for (int i = 0; i < 2; ++i)
        #pragma unroll
        for (int r = 0; r < 4; ++r) {
            const int m = m0 + wm + i * 16 + rr + r;
            #pragma unroll
            for (int j = 0; j < 4; ++j) {
                const int c = n0 + wn + j * 16 + fm;
                Yf[(size_t)m * 1024 + c] = acc[i][j][r] + bias[c];
            }
        }
}

// ---------------------------------------------------------------------------
// Table-driven RoPE on qh and kh (in place).  Pure HBM-bound.
// ---------------------------------------------------------------------------
__global__ __launch_bounds__(256) void rope_tab(_Float16* __restrict__ qh,
                                                _Float16* __restrict__ kh,
                                                const int* __restrict__ qpos,
                                                const int* __restrict__ kpos,
                                                const float2* __restrict__ tab)
{
    const int idx = blockIdx.x * 256 + threadIdx.x;
    const int row = idx >> 3;
    const int d0 = (idx & 7) * 4;               // 0,4,...,28

    _Float16* ptr; int p; float scale;
    if (row < 32768) {                          // q: 4*16*512 rows
        ptr = qh + (size_t)row * 64;
        p = qpos[(row >> 13) * 512 + (row & 511)];
        scale = 0.125f;
    } else {                                    // k: 4*16*2048 rows
        const int rk = row - 32768;
        ptr = kh + (size_t)rk * 64;
        p = kpos[(rk >> 15) * 2048 + (rk & 2047)];
        scale = 1.0f;
    }

    half4 x1 = *(const half4*)(ptr + d0);
    half4 x2 = *(const half4*)(ptr + d0 + 32);
    const float2* tb = tab + p * 32 + d0;
    half4 o1, o2;
    #pragma unroll
    for (int u = 0; u < 4; ++u) {
        const float2 cs = tb[u];
        const float a = (float)x1[u], b = (float)x2[u];
        o1[u] = (_Float16)((a * cs.x - b * cs.y) * scale);
        o2[u] = (_Float16)((b * cs.x + a * cs.y) * scale);
    }
    *(half4*)(ptr + d0)      = o1;
    *(half4*)(ptr + d0 + 32) = o2;
}

// ---------------------------------------------------------------------------
// Fused flash attention, key-half split.
// Grid 512 = qoct(8) x bh(64); 8 waves/block (512 thr).
// Wave w: q-tile qoct*4 + (w&3), key-half kh2 = w>>2 (keys [kh2*32,+32) of
// each shared 64-key tile).  All 8 waves share the triple-buffered K/V LDS
// tiles (staging 1 K + 1 V g2l call per wave per tile, steady vmcnt(2)).
// Fixed-max softmax => partials add: combine via LDS (sK/sV reuse) at end.
// ---------------------------------------------------------------------------
__global__ __launch_bounds__(512) void attn_fused(const _Float16* __restrict__ qh,
                                                  const _Float16* __restrict__ kh,
                                                  const _Float16* __restrict__ vt,
                                                  _Float16* __restrict__ xw16)
{
    __shared__ _Float16 sK[3][64 * 64];
    __shared__ _Float16 sV[3][64 * 64];
    __shared__ _Float16 ps2[8][16][34];

    const int tid = threadIdx.x;
    const int lane = tid & 63, w = tid >> 6;    // 8 waves
    const int qt4 = w & 3;                      // q-tile within block
    const int kh2 = w >> 2;                     // key-half 0/1
    const int bhi = blockIdx.x & 63;            // XCD key
    const int qoct = blockIdx.x >> 6;           // 0..7
    const size_t bh = (size_t)bhi;
    const int qt = qoct * 4 + qt4;              // q-tile 0..31 (16 queries)

    const int fm = lane & 15;
    const int quad = lane >> 4;
    const int fq = quad * 8;

    const _Float16* kb = kh + bh * NK * 64;
    const _Float16* vb = vt + bh * (size_t)64 * NK;

    // staging: wave w covers tile rows w*8 + r0 (K: keys, V: d-rows)
    const int r0 = lane >> 3;
    const int c4 = lane & 7;
    const int sch = c4 ^ r0;
    const _Float16* gK = kb + (size_t)(w * 8 + r0) * 64 + sch * 8;
    const _Float16* gV = vb + (size_t)(w * 8 + r0) * NK + sch * 8;

#define STAGE(bf, t) do {                                             \
        g2l16(gK + (size_t)(t) * 4096, &sK[bf][(w * 8) * 64]);        \
        g2l16(gV + (t) * 64,           &sV[bf][(w * 8) * 64]);        \
    } while (0)

    const _Float16* qb = qh + (bh * NQ + (size_t)qt * 16) * 64;
    half8 aq[2];
    aq[0] = *(const half8*)(qb + (size_t)fm * 64 + fq);
    aq[1] = *(const half8*)(qb + (size_t)fm * 64 + 32 + fq);

    float l_acc[4] = {};
    float4v O[4];
    #pragma unroll
    for (int j = 0; j < 4; ++j)
        #pragma unroll
        for (int e = 0; e < 4; ++e) O[j][e] = 0.0f;

    const float4v z4 = {0.0f, 0.0f, 0.0f, 0.0f};

    STAGE(0, 0);
    STAGE(1, 1);

    for (int it = 0; it < 32; ++it) {
        const int cur = it % 3;

        // own 2 calls of tile it retired; stage(it+1) stays in flight.
        if (it < 31) asm volatile("s_waitcnt vmcnt(2)" ::: "memory");
        else         asm volatile("s_waitcnt vmcnt(0)" ::: "memory");
        __builtin_amdgcn_sched_barrier(0);
        __builtin_amdgcn_s_barrier();           // tile it visible to all waves
        __builtin_amdgcn_sched_barrier(0);

        if (it + 2 < 32)
            STAGE((it + 2) % 3, it + 2);        // overwrites buf (it-1)%3: safe

        const _Float16* Kc = sK[cur];
        const _Float16* Vc = sV[cur];

        // QK^T for this wave's key half: global key-tile j = kh2*2 + jl
        half8 bk[2][2];
        #pragma unroll
        for (int jl = 0; jl < 2; ++jl)
            #pragma unroll
            for (int ks = 0; ks < 2; ++ks)
                bk[jl][ks] = *(const half8*)&Kc[((kh2 * 2 + jl) * 16 + fm) * 64 + (((ks * 4 + quad) ^ (fm & 7)) * 8)];

        float4v s[2];
        __builtin_amdgcn_s_setprio(1);
        #pragma unroll
        for (int jl = 0; jl < 2; ++jl) {
            s[jl] = __builtin_amdgcn_mfma_f32_16x16x32_f16(aq[0], bk[jl][0], z4, 0, 0, 0);
            s[jl] = __builtin_amdgcn_mfma_f32_16x16x32_f16(aq[1], bk[jl][1], s[jl], 0, 0, 0);
        }
        __builtin_amdgcn_s_setprio(0);

        // V fragments for this wave's key half (k-slice = kh2), all 4 d-tiles
        half8 bv[4];
        #pragma unroll
        for (int j = 0; j < 4; ++j)
            bv[j] = *(const half8*)&Vc[(j * 16 + fm) * 64 + (((kh2 * 4 + quad) ^ (fm & 7)) * 8)];

        // P = exp(s) (scores pre-scaled by 0.125 in rope; fixed max 0 safe)
        #pragma unroll
        for (int jl = 0; jl < 2; ++jl)
            #pragma unroll
            for (int r = 0; r < 4; ++r) {
                const float p = __expf(s[jl][r]);
                l_acc[r] += p;
                ps2[w][quad * 4 + r][16 * jl + fm] = (_Float16)p;
            }

        __builtin_amdgcn_s_setprio(1);
        {
            half8 pa = *(const half8*)&ps2[w][fm][fq];
            #pragma unroll
            for (int j = 0; j < 4; ++j)
                O[j] = __builtin_amdgcn_mfma_f32_16x16x32_f16(pa, bv[j], O[j], 0, 0, 0);
        }
        __builtin_amdgcn_s_setprio(0);
    }
#undef STAGE

    // l reduction over the 16 fm lanes of each quad.
    float lr[4];
    #pragma unroll
    for (int r = 0; r < 4; ++r) {
        float l = l_acc[r];
        l += __shfl_xor(l, 1);
        l += __shfl_xor(l, 2);
        l += __shfl_xor(l, 4);
        l += __shfl_xor(l, 8);
        lr[r] = l;
    }

    __syncthreads();                            // all compute done; reuse LDS

    float* cb = (float*)sK;                     // [4][16][64] O partials
    float* lb = (float*)sV;                     // [4][16]     l partials
    if (kh2 == 1) {
        #pragma unroll
        for (int r = 0; r < 4; ++r) {
            const int qr = quad * 4 + r;
            #pragma unroll
            for (int j = 0; j < 4; ++j)
                cb[qt4 * 1024 + qr * 64 + j * 16 + fm] = O[j][r];
            if (fm == 0) lb[qt4 * 16 + qr] = lr[r];
        }
    }
    __syncthreads();
    if (kh2 == 0) {
        #pragma unroll
        for (int r = 0; r < 4; ++r) {
            const int qr = quad * 4 + r;
            const float inv = 1.0f / (lr[r] + lb[qt4 * 16 + qr]);
            const int row = (bhi >> 4) * 512 + qt * 16 + qr;
            #pragma unroll
            for (int j = 0; j < 4; ++j) {
                const float o = O[j][r] + cb[qt4 * 1024 + qr * 64 + j * 16 + fm];
                xw16[(size_t)row * 1024 + (bhi & 15) * 64 + j * 16 + fm] = (_Float16)(o * inv);
            }
        }
    }
}

// ---------------------------------------------------------------------------
extern "C" void kernel_launch(void* const* d_in, const int* in_sizes, int n_in,
                              void* d_out, int out_size, void* d_ws, size_t ws_size,
                              hipStream_t stream)
{
    const float* query = (const float*)d_in[0];
    const float* key   = (const float*)d_in[1];
    const float* value = (const float*)d_in[2];
    const int*   qpos  = (const int*)d_in[3];
    const int*   kpos  = (const int*)d_in[4];
    const float* Wq    = (const float*)d_in[5];
    const float* Wk    = (const float*)d_in[6];
    const float* Wv    = (const float*)d_in[7];
    const float* Wp    = (const float*)d_in[8];
    const float* bp    = (const float*)d_in[9];
    float* out = (float*)d_out;

    // ws layout (MiB), 80 total:
    //  0..16 : xk16 [8192][1024] fp16 (free after gemm_qkv)
    // 16..32 : xv16 [8192][1024] fp16 (free after gemm_qkv)
    // 32..36 : xq16 [2048][1024] fp16 -> reused as xw16 (attn out)
    // 36..44 : W16 x4 slots (Wq,Wk,Wv,Wp)
    // 44..48 : qh  [B,H,512,64] fp16
    // 48..64 : kh  [B,H,2048,64] fp16
    // 64..80 : vt  [B,H,64,2048] fp16
    // rope table tab (512KB) lives in d_out (dead until gemm_out overwrites).
    char* ws = (char*)d_ws;
    _Float16* xk16  = (_Float16*)(ws);
    _Float16* xv16  = (_Float16*)(ws + (16u << 20));
    _Float16* xq16  = (_Float16*)(ws + (32u << 20));
    _Float16* W16   = (_Float16*)(ws + (36u << 20));
    _Float16* qhp   = (_Float16*)(ws + (44u << 20));
    _Float16* khp   = (_Float16*)(ws + (48u << 20));
    _Float16* vtp   = (_Float16*)(ws + (64u << 20));
    float2*   tab   = (float2*)d_out;            // scratch until gemm_out

    cvt_all<<<22784, 256, 0, stream>>>(Wq, Wk, Wv, Wp, query, key, value,
                                       W16, xq16, xk16, xv16, tab);

    gemm_qkv<<<1152, 256, 0, stream>>>(xq16, xk16, xv16, W16, qhp, khp, vtp);

    rope_tab<<<5120, 256, 0, stream>>>(qhp, khp, qpos, kpos, tab);

    attn_fused<<<512, 512, 0, stream>>>(qhp, khp, vtp, xq16);

    gemm_out<<<dim3(8, 32), 256, 0, stream>>>(xq16, W16 + (3u << 20), out, bp);
}